// Round 6
// baseline (151.297 us; speedup 1.0000x reference)
//
#include <hip/hip_runtime.h>
#include <hip/hip_bf16.h>
#include <stdint.h>

typedef __attribute__((ext_vector_type(8))) short short8;
typedef __attribute__((ext_vector_type(4))) float f32x4;
typedef __attribute__((ext_vector_type(4))) float float4v;
typedef __attribute__((ext_vector_type(4))) int int4v;

#define IN_F 2048
#define OUT_F 8192
#define M_DIM 4096        // BATCH * SEQ
#define NT (IN_F / 64)    // 32 K-tiles of BK=64

__device__ __constant__ float c_lut[15] = {
    -1.0f, -0.5f, -0.333333f, -0.2f, -0.142857f, -0.090909f, -0.076923f,
    0.0f, 0.076923f, 0.090909f, 0.142857f, 0.2f, 0.333333f, 0.5f, 1.0f};

__device__ inline ushort f2bf(float f) {
    union { float f; uint32_t u; } v; v.f = f;
    uint32_t u = v.u;
    u += 0x7fffu + ((u >> 16) & 1u);
    return (ushort)(u >> 16);
}

__device__ inline void gload_lds16(const void* g, void* l) {
    __builtin_amdgcn_global_load_lds(
        (const __attribute__((address_space(1))) void*)(uintptr_t)g,
        (__attribute__((address_space(3))) void*)(uint32_t)(uintptr_t)l,
        16, 0, 0);
}

// ---------------- dequant: grid_indices[int32] -> w_bf16 [OUT_F][IN_F] ----------------
__global__ __launch_bounds__(256) void dequant_w(const int* __restrict__ gi,
                                                 const float* __restrict__ scale_p,
                                                 ushort* __restrict__ w) {
    __shared__ float lut_s[16];
    if (threadIdx.x < 16) {
        float s = scale_p[0];
        lut_s[threadIdx.x] = (threadIdx.x < 15 ? c_lut[threadIdx.x] : 0.0f) * s;
    }
    __syncthreads();
    size_t t = (size_t)blockIdx.x * 256 + threadIdx.x;
    const int4v* src = (const int4v*)gi;
    int4v v0 = src[t * 2];
    int4v v1 = src[t * 2 + 1];
    short8 o;
    o[0] = (short)f2bf(lut_s[v0.x]);
    o[1] = (short)f2bf(lut_s[v0.y]);
    o[2] = (short)f2bf(lut_s[v0.z]);
    o[3] = (short)f2bf(lut_s[v0.w]);
    o[4] = (short)f2bf(lut_s[v1.x]);
    o[5] = (short)f2bf(lut_s[v1.y]);
    o[6] = (short)f2bf(lut_s[v1.z]);
    o[7] = (short)f2bf(lut_s[v1.w]);
    ((short8*)w)[t] = o;
}

// ---------------- x fp32 -> bf16 [M_DIM][IN_F] ----------------
__global__ __launch_bounds__(256) void xconv(const float* __restrict__ x,
                                             ushort* __restrict__ xb) {
    size_t t = (size_t)blockIdx.x * 256 + threadIdx.x;
    const float4v* src = (const float4v*)x;
    float4v v0 = src[t * 2];
    float4v v1 = src[t * 2 + 1];
    short8 o;
    o[0] = (short)f2bf(v0.x);
    o[1] = (short)f2bf(v0.y);
    o[2] = (short)f2bf(v0.z);
    o[3] = (short)f2bf(v0.w);
    o[4] = (short)f2bf(v1.x);
    o[5] = (short)f2bf(v1.y);
    o[6] = (short)f2bf(v1.z);
    o[7] = (short)f2bf(v1.w);
    ((short8*)xb)[t] = o;
}

// ---------------- GEMM: C[M][N] = A[M][K] * B[N][K]^T (bf16 in, fp32 out) ----------------
// m201-aligned: 256x256 tile, BK=64, 8 waves (2M x 4N), dbuf 128 KiB LDS,
// 4 phases/K-tile, each {pre-barrier ds_read half h_p + stage h_p(t+1) ->
// barrier -> 16 MFMA (setprio) -> barrier}. vmcnt(4) only at ph2/ph4 (ledger:
// each retires the halves read 1-2 phases later; waits land ~1200cyc after
// issue). Halves: h1=Aq0, h2=Bq0, h3=Aq1, h4=Bq1. MFMA rotated one phase:
// ph1=Q(1,1) prev tile, ph2=Q(0,0), ph3=Q(1,0), ph4=Q(0,1). XOR read-swizzle
// slot^=(row&7) with inverse-swizzled global source. Bijective XCD swizzle.
__global__ __launch_bounds__(512, 2) void gemm4p(const ushort* __restrict__ A,
                                                 const ushort* __restrict__ Bm,
                                                 float* __restrict__ C) {
    __shared__ ushort lds[2][2][256][64];   // [dbuf][A/B][row][col] = 128 KiB

    const int tid  = threadIdx.x;
    const int lane = tid & 63;
    const int wid  = tid >> 6;
    const int wm = wid >> 2;   // 0..1 : 128-row band
    const int wn = wid & 3;    // 0..3 : 64-col band
    const int g = lane >> 4;
    const int r = lane & 15;

    // XCD-aware bijective swizzle: grid=512, 8 XCDs -> 64 contiguous blocks each.
    // Per XCD: 4 bn-panels (4 MB B, L2-resident) x 16 bm.
    const int bid  = (int)blockIdx.x;
    const int bidx = (bid & 7) * 64 + (bid >> 3);
    const int bm = (bidx & 15) * 256;   // M fast -> neighbors share B panel
    const int bn = (bidx >> 4) * 256;

    // A staging: thread covers rows (tid>>3) + {0,128} (h1) / +{64,192} (h3).
    // Inverse-swizzled source col: ((tid&7) ^ (row&7))*8; row&7 == (tid>>3)&7.
    const int arow = tid >> 3;
    const int acol = ((tid & 7) ^ (arow & 7)) * 8;
    const ushort* a_sbase = A + (size_t)(bm + arow) * IN_F + acol;

    // B staging: wave covers band (wid>>1), 16-row group (wid&1)*16, row lane>>3.
    const int brow0 = (wid >> 1) * 64 + (wid & 1) * 16 + (lane >> 3);
    const int bcol  = ((lane & 7) ^ (lane >> 3)) * 8;
    const ushort* b_sbase = Bm + (size_t)(bn + brow0) * IN_F + bcol;

#define VMCNT4 asm volatile("s_waitcnt vmcnt(4)" ::: "memory")
#define VMCNT0 asm volatile("s_waitcnt vmcnt(0)" ::: "memory")
#define BARRIER()                                                         \
    do {                                                                  \
        asm volatile("" ::: "memory");                                    \
        __builtin_amdgcn_s_barrier();                                     \
        asm volatile("" ::: "memory");                                    \
    } while (0)

#define STAGE_A(buf_, q_, t_)                                             \
    do {                                                                  \
        const ushort* _s = a_sbase + (size_t)(t_) * 64 + (size_t)(q_) * 64 * IN_F; \
        ushort* _d = &lds[buf_][0][(q_) * 64][0] + tid * 8;               \
        gload_lds16(_s, _d);                                              \
        gload_lds16(_s + (size_t)128 * IN_F, _d + 128 * 64);              \
    } while (0)

#define STAGE_B(buf_, q_, t_)                                             \
    do {                                                                  \
        const ushort* _s = b_sbase + (size_t)(t_) * 64 + (size_t)(q_) * 32 * IN_F; \
        ushort* _d = &lds[buf_][1][brow0 + (q_) * 32][0] + (lane & 7) * 8; \
        gload_lds16(_s, _d);                                              \
        gload_lds16(_s + (size_t)8 * IN_F, _d + 8 * 64);                  \
    } while (0)

#define READ_AQ(c_, qa_, dst_)                                            \
    _Pragma("unroll")                                                     \
    for (int f = 0; f < 4; ++f)                                           \
        _Pragma("unroll")                                                 \
        for (int ks = 0; ks < 2; ++ks)                                    \
            dst_[f][ks] = *(const short8*)&lds[c_][0][wm * 128 + (qa_) * 64 + f * 16 + r][((ks * 4 + g) ^ (r & 7)) * 8];

#define READ_BQ(c_, qb_, dst_)                                            \
    _Pragma("unroll")                                                     \
    for (int f = 0; f < 2; ++f)                                           \
        _Pragma("unroll")                                                 \
        for (int ks = 0; ks < 2; ++ks)                                    \
            dst_[f][ks] = *(const short8*)&lds[c_][1][wn * 64 + (qb_) * 32 + f * 16 + r][((ks * 4 + g) ^ (r & 7)) * 8];

#define MFMA_Q(qa_, qb_, asrc_, bsrc_)                                    \
    do {                                                                  \
        __builtin_amdgcn_s_setprio(1);                                    \
        _Pragma("unroll")                                                 \
        for (int f = 0; f < 4; ++f)                                       \
            _Pragma("unroll")                                             \
            for (int f2 = 0; f2 < 2; ++f2)                                \
                _Pragma("unroll")                                         \
                for (int ks = 0; ks < 2; ++ks)                            \
                    acc[(qa_) * 4 + f][(qb_) * 2 + f2] =                  \
                        __builtin_amdgcn_mfma_f32_16x16x32_bf16(          \
                            asrc_[f][ks], bsrc_[f2][ks],                  \
                            acc[(qa_) * 4 + f][(qb_) * 2 + f2], 0, 0, 0); \
        __builtin_amdgcn_s_setprio(0);                                    \
    } while (0)

#define TILE_STEADY(c_, t_, P1_)                                          \
    do {                                                                  \
        /* ph1 */                                                         \
        READ_AQ(c_, 0, aq0);                                              \
        STAGE_A((c_) ^ 1, 0, (t_) + 1);                                   \
        BARRIER();                                                        \
        if (P1_) MFMA_Q(1, 1, aq1, bq1);                                  \
        BARRIER();                                                        \
        /* ph2 */                                                         \
        READ_BQ(c_, 0, bq0);                                              \
        STAGE_B((c_) ^ 1, 0, (t_) + 1);                                   \
        VMCNT4;                                                           \
        BARRIER();                                                        \
        MFMA_Q(0, 0, aq0, bq0);                                           \
        BARRIER();                                                        \
        /* ph3 */                                                         \
        READ_AQ(c_, 1, aq1);                                              \
        STAGE_A((c_) ^ 1, 1, (t_) + 1);                                   \
        BARRIER();                                                        \
        MFMA_Q(1, 0, aq1, bq0);                                           \
        BARRIER();                                                        \
        /* ph4 */                                                         \
        READ_BQ(c_, 1, bq1);                                              \
        STAGE_B((c_) ^ 1, 1, (t_) + 1);                                   \
        VMCNT4;                                                           \
        BARRIER();                                                        \
        MFMA_Q(0, 1, aq0, bq1);                                           \
        BARRIER();                                                        \
    } while (0)

#define TILE_LAST(c_)                                                     \
    do {                                                                  \
        READ_AQ(c_, 0, aq0);                                              \
        BARRIER();                                                        \
        MFMA_Q(1, 1, aq1, bq1);                                           \
        BARRIER();                                                        \
        READ_BQ(c_, 0, bq0);                                              \
        VMCNT0;                                                           \
        BARRIER();                                                        \
        MFMA_Q(0, 0, aq0, bq0);                                           \
        BARRIER();                                                        \
        READ_AQ(c_, 1, aq1);                                              \
        BARRIER();                                                        \
        MFMA_Q(1, 0, aq1, bq0);                                           \
        READ_BQ(c_, 1, bq1);                                              \
        MFMA_Q(0, 1, aq0, bq1);                                           \
        MFMA_Q(1, 1, aq1, bq1);                                           \
    } while (0)

    f32x4 acc[8][4] = {};
    short8 aq0[4][2], aq1[4][2], bq0[2][2], bq1[2][2];

    // prologue: stage tile 0 (h1..h4); retire h1,h2 before first reads.
    STAGE_A(0, 0, 0);
    STAGE_B(0, 0, 0);
    STAGE_A(0, 1, 0);
    STAGE_B(0, 1, 0);
    VMCNT4;
    BARRIER();

    TILE_STEADY(0, 0, 0);                 // tile 0: no prev-tile MFMA at ph1
    for (int tt = 1; tt < NT - 1; tt += 2) {
        TILE_STEADY(1, tt, 1);            // tiles 1..30 (tile 30 stages tile 31)
        TILE_STEADY(0, tt + 1, 1);
    }
    TILE_LAST(1);                          // tile 31

    // epilogue: C/D layout col = lane&15, row = (lane>>4)*4 + reg  [verified m89/m91]
    const int crow0 = bm + wm * 128 + g * 4;
    const int ccol0 = bn + wn * 64 + r;
#pragma unroll
    for (int mi = 0; mi < 8; ++mi)
#pragma unroll
        for (int ni = 0; ni < 4; ++ni)
#pragma unroll
            for (int j = 0; j < 4; ++j)
                C[(size_t)(crow0 + mi * 16 + j) * OUT_F + ccol0 + ni * 16] = acc[mi][ni][j];

#undef TILE_LAST
#undef TILE_STEADY
#undef MFMA_Q
#undef READ_BQ
#undef READ_AQ
#undef STAGE_B
#undef STAGE_A
#undef BARRIER
#undef VMCNT0
#undef VMCNT4
}

extern "C" void kernel_launch(void* const* d_in, const int* in_sizes, int n_in,
                              void* d_out, int out_size, void* d_ws, size_t ws_size,
                              hipStream_t stream) {
    const float* x     = (const float*)d_in[0];
    const int*   gi    = (const int*)d_in[1];
    const float* scale = (const float*)d_in[2];
    float* out = (float*)d_out;

    ushort* wbf = (ushort*)d_ws;                          // 32 MB
    ushort* xbf = (ushort*)d_ws + (size_t)OUT_F * IN_F;   // +16 MB

    dequant_w<<<8192, 256, 0, stream>>>(gi, scale, wbf);
    xconv<<<4096, 256, 0, stream>>>(x, xbf);
    gemm4p<<<(M_DIM / 256) * (OUT_F / 256), 512, 0, stream>>>(xbf, wbf, out);
}